// Round 1
// baseline (149.216 us; speedup 1.0000x reference)
//
#include <hip/hip_runtime.h>

// GuidanceController: per agent, screened-Poisson Jacobi (50 iters) on a
// 128x128 grid with one Dirichlet cell, bilinear-sample 80 traj points,
// combine with analytic drift energies, global scalar sum.
//
// Design: 1 block = 1 agent. Field lives in LDS (row stride 132 floats ->
// 2-way bank aliasing only, which is free on wave64). Each thread owns a
// 16-wide row segment kept in registers across iterations; per iter it reads
// only up/down rows (4x float4 each) + 2 halo scalars from LDS.

#define GR     128
#define STRIDE 132          // padded row stride (floats); keeps 16B alignment
#define NITER  50
#define TPTS   80

__global__ __launch_bounds__(1024, 4)
void guidance_kernel(const float* __restrict__ pos,    // [N,80,2]
                     const float* __restrict__ gw,     // [N,3]
                     const float* __restrict__ head,   // [N,2]
                     float* __restrict__ out)
{
    __shared__ float u[GR * STRIDE];   // 67584 B
    __shared__ float red[128];

    const int n   = blockIdx.x;
    const int tid = threadIdx.x;
    const int tx  = tid & 7;    // 8 segments of 16 cols
    const int ty  = tid >> 3;   // 128 rows
    const int c0  = tx << 4;

    // ---- per-agent scalars (computed by every thread; cheap, cached) ----
    const float hx = head[2*n+0], hy = head[2*n+1];
    const float hnorm = sqrtf(hx*hx + hy*hy);
    const float ih  = 1.0f / fmaxf(hnorm, 1e-12f);
    const float hnx = hx * ih, hny = hy * ih;
    const float p0x = pos[n*160 + 0];
    const float p0y = pos[n*160 + 1];

    const float w_lane  = gw[3*n+0];
    const float w_left  = gw[3*n+1];
    const float w_right = gw[3*n+2];

    // Analytic energies + output are handled by thread 0 at the end.
    // If w_lane is negligible the whole field solve is dead work -> skip it.
    const bool need_field = (w_lane > 1e-4f);

    const float DXf = (float)(100.0 / 127.0);
    const float gclx = fminf(fmaxf(p0x + hnx * 50.0f, -50.0f), 50.0f);
    const float gcly = fminf(fmaxf(p0y + hny * 50.0f, -50.0f), 50.0f);
    const int gxi = (int)((gclx + 50.0f) / DXf);   // >=0, <=127 by construction
    const int gyi = (int)((gcly + 50.0f) / DXf);

    const float INV_DENOM =
        (float)(1.0 / (4.0 + 0.01 * (100.0/127.0) * (100.0/127.0)));

    float sampled_sum = 0.0f;

    if (need_field) {
        const bool own_row   = (ty == gyi);
        const int  src_local = gxi - c0;    // valid only if in [0,16)

        // ---- init: 0.5 everywhere, 1.0 at source cell ----
        float c[16];
#pragma unroll
        for (int i = 0; i < 16; ++i)
            c[i] = (own_row && i == src_local) ? 1.0f : 0.5f;

        float4* urow = reinterpret_cast<float4*>(&u[ty * STRIDE + c0]);
#pragma unroll
        for (int q = 0; q < 4; ++q)
            urow[q] = make_float4(c[4*q+0], c[4*q+1], c[4*q+2], c[4*q+3]);
        __syncthreads();

        const float4* uUp = reinterpret_cast<const float4*>(&u[(ty - 1) * STRIDE + c0]);
        const float4* uDn = reinterpret_cast<const float4*>(&u[(ty + 1) * STRIDE + c0]);
        const float*  uL  = &u[ty * STRIDE + c0 - 1];
        const float*  uR  = &u[ty * STRIDE + c0 + 16];
        const bool hasUp = (ty > 0), hasDn = (ty < GR - 1);
        const bool hasL  = (tx > 0), hasR  = (tx < 7);

        for (int it = 0; it < NITER; ++it) {
            float up[16], dn[16];
            if (hasUp) {
#pragma unroll
                for (int q = 0; q < 4; ++q) {
                    const float4 v = uUp[q];
                    up[4*q+0]=v.x; up[4*q+1]=v.y; up[4*q+2]=v.z; up[4*q+3]=v.w;
                }
            } else {
#pragma unroll
                for (int i = 0; i < 16; ++i) up[i] = 0.0f;  // zero padding
            }
            if (hasDn) {
#pragma unroll
                for (int q = 0; q < 4; ++q) {
                    const float4 v = uDn[q];
                    dn[4*q+0]=v.x; dn[4*q+1]=v.y; dn[4*q+2]=v.z; dn[4*q+3]=v.w;
                }
            } else {
#pragma unroll
                for (int i = 0; i < 16; ++i) dn[i] = 0.0f;
            }
            const float lh = hasL ? uL[0] : 0.0f;
            const float rh = hasR ? uR[0] : 0.0f;

            float nv[16];
#pragma unroll
            for (int i = 0; i < 16; ++i) {
                const float l = (i == 0)  ? lh : c[i-1];
                const float r = (i == 15) ? rh : c[i+1];
                nv[i] = (l + r + up[i] + dn[i]) * INV_DENOM;
            }
            if (own_row) {
#pragma unroll
                for (int i = 0; i < 16; ++i)
                    if (i == src_local) nv[i] = 1.0f;   // Dirichlet cell
            }
            __syncthreads();   // all reads of old field done
#pragma unroll
            for (int q = 0; q < 4; ++q)
                urow[q] = make_float4(nv[4*q+0], nv[4*q+1], nv[4*q+2], nv[4*q+3]);
#pragma unroll
            for (int i = 0; i < 16; ++i) c[i] = nv[i];
            __syncthreads();   // all writes visible for next iter
        }

        // ---- bilinear sampling of 80 trajectory points ----
        float partial = 0.0f;
        if (tid < TPTS) {
            const float px = pos[n*160 + 2*tid + 0];
            const float py = pos[n*160 + 2*tid + 1];
            const float txn = (px + 50.0f) / 100.0f * 2.0f - 1.0f;
            const float tyn = (py + 50.0f) / 100.0f * 2.0f - 1.0f;
            float fx = (txn + 1.0f) * 0.5f * 127.0f;
            float fy = (tyn + 1.0f) * 0.5f * 127.0f;
            fx = fminf(fmaxf(fx, 0.0f), 127.0f);
            fy = fminf(fmaxf(fy, 0.0f), 127.0f);
            const float x0 = floorf(fx), y0 = floorf(fy);
            const float wx = fx - x0,    wy = fy - y0;
            int x0i = (int)x0; x0i = x0i < 0 ? 0 : (x0i > 127 ? 127 : x0i);
            int y0i = (int)y0; y0i = y0i < 0 ? 0 : (y0i > 127 ? 127 : y0i);
            const int x1i = (x0i + 1 > 127) ? 127 : x0i + 1;
            const int y1i = (y0i + 1 > 127) ? 127 : y0i + 1;
            const float v00 = u[y0i*STRIDE + x0i];
            const float v01 = u[y0i*STRIDE + x1i];
            const float v10 = u[y1i*STRIDE + x0i];
            const float v11 = u[y1i*STRIDE + x1i];
            partial = v00*(1.0f-wx)*(1.0f-wy) + v01*wx*(1.0f-wy)
                    + v10*(1.0f-wx)*wy        + v11*wx*wy;
        }
        if (tid < 128) red[tid] = (tid < TPTS) ? partial : 0.0f;
        __syncthreads();
        if (tid == 0) {
            float s = 0.0f;
            for (int i = 0; i < 128; ++i) s += red[i];
            sampled_sum = s;
        }
    }

    // ---- analytic energies + global reduction ----
    if (tid == 0) {
        const float dlx = pos[n*160 + 2*(TPTS-1) + 0] - p0x;
        const float dly = pos[n*160 + 2*(TPTS-1) + 1] - p0y;
        const float left_drift = dlx * (-hny) + dly * hnx;
        const float e_left  = -left_drift + 2.0f * fmaxf(-left_drift, 0.0f);
        const float e_right =  left_drift + 2.0f * fmaxf( left_drift, 0.0f);
        const float e_lane  = need_field ? -sampled_sum : 0.0f;
        atomicAdd(out, w_lane*e_lane + w_left*e_left + w_right*e_right);
    }
}

extern "C" void kernel_launch(void* const* d_in, const int* in_sizes, int n_in,
                              void* d_out, int out_size, void* d_ws, size_t ws_size,
                              hipStream_t stream) {
    const float* pos  = (const float*)d_in[0];   // agent_positions_flat [N,80,2]
    const float* gw   = (const float*)d_in[1];   // guidance_weights    [N,3]
    const float* head = (const float*)d_in[2];   // initial_headings    [N,2]
    float* out = (float*)d_out;

    const int N = in_sizes[0] / 160;             // N*T*2 / (80*2) = 384

    hipMemsetAsync(out, 0, sizeof(float) * out_size, stream);
    guidance_kernel<<<N, 1024, 0, stream>>>(pos, gw, head, out);
}

// Round 2
// 120.632 us; speedup vs baseline: 1.2370x; 1.2370x over previous
//
#include <hip/hip_runtime.h>

// GuidanceController: per agent, screened-Poisson Jacobi (50 iters) on 128x128,
// bilinear-sample 80 traj points, combine with analytic drift energies, sum.
//
// Round-2 design: 1 block = 1 agent, 512 threads, each owns a 4x8 register
// tile (32 tile-rows x 16 tile-cols). Halo exchange via 6 float4 edge buffers
// indexed by tid -> every hot-loop LDS op is lane-contiguous b128 (conflict-
// free). Interior neighbors come from registers. Field written to LDS once
// after the loop (aliasing the edge buffers) for sampling.

#define GR      128
#define FSTRIDE 132
#define NITER   50
#define TPTS    80

__global__ __launch_bounds__(512, 4)
void guidance_kernel(const float* __restrict__ pos,    // [N,80,2]
                     const float* __restrict__ gw,     // [N,3]
                     const float* __restrict__ head,   // [N,2]
                     float* __restrict__ out)
{
    __shared__ __align__(16) char smem[GR * FSTRIDE * 4];   // 67584 B
    __shared__ float red[TPTS];

    // edge buffers (alias the low part of smem; dead once the loop ends)
    float4* rt0 = (float4*)(smem);            // top-row  cols 0..3
    float4* rt1 = (float4*)(smem +  8192);    // top-row  cols 4..7
    float4* rb0 = (float4*)(smem + 16384);    // bot-row  cols 0..3
    float4* rb1 = (float4*)(smem + 24576);    // bot-row  cols 4..7
    float4* cle = (float4*)(smem + 32768);    // left col, rows 0..3
    float4* cre = (float4*)(smem + 40960);    // right col, rows 0..3
    float*  u   = (float*)smem;               // final field, stride 132

    const int n   = blockIdx.x;
    const int tid = threadIdx.x;
    const int cx  = tid & 15;     // 16 tile-cols of 8
    const int cy  = tid >> 4;     // 32 tile-rows of 4
    const int row0 = cy << 2;
    const int col0 = cx << 3;

    // ---- per-agent scalars ----
    const float hx = head[2*n+0], hy = head[2*n+1];
    const float ih  = 1.0f / fmaxf(sqrtf(hx*hx + hy*hy), 1e-12f);
    const float hnx = hx * ih, hny = hy * ih;
    const float p0x = pos[n*160 + 0];
    const float p0y = pos[n*160 + 1];

    const float w_lane  = gw[3*n+0];
    const float w_left  = gw[3*n+1];
    const float w_right = gw[3*n+2];
    const bool need_field = (w_lane > 1e-4f);   // block-uniform

    const float DXf = (float)(100.0 / 127.0);
    const float gclx = fminf(fmaxf(p0x + hnx * 50.0f, -50.0f), 50.0f);
    const float gcly = fminf(fmaxf(p0y + hny * 50.0f, -50.0f), 50.0f);
    const int gxi = (int)((gclx + 50.0f) / DXf);
    const int gyi = (int)((gcly + 50.0f) / DXf);

    const float INV_DENOM =
        (float)(1.0 / (4.0 + 0.01 * (100.0/127.0) * (100.0/127.0)));

    float sampled_sum = 0.0f;

    if (need_field) {
        // ---- init: 0.5 everywhere, 1.0 at source cell ----
        float c[4][8];
#pragma unroll
        for (int r = 0; r < 4; ++r)
#pragma unroll
            for (int j = 0; j < 8; ++j)
                c[r][j] = 0.5f;
        const int sr = gyi - row0;
        const int sc = gxi - col0;
        const bool own = (sr >= 0 && sr < 4 && sc >= 0 && sc < 8);
        if (own) {
#pragma unroll
            for (int r = 0; r < 4; ++r)
#pragma unroll
                for (int j = 0; j < 8; ++j)
                    if (r == sr && j == sc) c[r][j] = 1.0f;
        }

        const bool hasT = (cy > 0), hasB = (cy < 31);
        const bool hasL = (cx > 0), hasR = (cx < 15);
        const float4 z4 = make_float4(0.f, 0.f, 0.f, 0.f);

        for (int it = 0; it < NITER; ++it) {
            // ---- publish edges (all stride-1 b128, conflict-free) ----
            rt0[tid] = make_float4(c[0][0], c[0][1], c[0][2], c[0][3]);
            rt1[tid] = make_float4(c[0][4], c[0][5], c[0][6], c[0][7]);
            rb0[tid] = make_float4(c[3][0], c[3][1], c[3][2], c[3][3]);
            rb1[tid] = make_float4(c[3][4], c[3][5], c[3][6], c[3][7]);
            cle[tid] = make_float4(c[0][0], c[1][0], c[2][0], c[3][0]);
            cre[tid] = make_float4(c[0][7], c[1][7], c[2][7], c[3][7]);
            __syncthreads();

            // ---- gather halos (shifted but still lane-contiguous) ----
            float th[8], bh[8], lh[4], rh[4];
            {
                float4 a = hasT ? rb0[tid - 16] : z4;
                float4 b = hasT ? rb1[tid - 16] : z4;
                th[0]=a.x; th[1]=a.y; th[2]=a.z; th[3]=a.w;
                th[4]=b.x; th[5]=b.y; th[6]=b.z; th[7]=b.w;
                a = hasB ? rt0[tid + 16] : z4;
                b = hasB ? rt1[tid + 16] : z4;
                bh[0]=a.x; bh[1]=a.y; bh[2]=a.z; bh[3]=a.w;
                bh[4]=b.x; bh[5]=b.y; bh[6]=b.z; bh[7]=b.w;
                a = hasL ? cre[tid - 1] : z4;
                lh[0]=a.x; lh[1]=a.y; lh[2]=a.z; lh[3]=a.w;
                a = hasR ? cle[tid + 1] : z4;
                rh[0]=a.x; rh[1]=a.y; rh[2]=a.z; rh[3]=a.w;
            }
            __syncthreads();   // reads done; next iter may overwrite edges

            // ---- in-place Jacobi update (registers only) ----
            float prev[8];
#pragma unroll
            for (int r = 0; r < 4; ++r) {
                float cur[8];
#pragma unroll
                for (int j = 0; j < 8; ++j) cur[j] = c[r][j];
#pragma unroll
                for (int j = 0; j < 8; ++j) {
                    const float up = (r == 0) ? th[j] : prev[j];
                    const float dn = (r == 3) ? bh[j] : c[r+1][j];
                    const float lf = (j == 0) ? lh[r] : cur[j-1];
                    const float rt = (j == 7) ? rh[r] : cur[j+1];
                    c[r][j] = (lf + rt + up + dn) * INV_DENOM;
                }
#pragma unroll
                for (int j = 0; j < 8; ++j) prev[j] = cur[j];
            }
            if (own) {
#pragma unroll
                for (int r = 0; r < 4; ++r)
#pragma unroll
                    for (int j = 0; j < 8; ++j)
                        if (r == sr && j == sc) c[r][j] = 1.0f;
            }
        }

        // ---- dump field to LDS (one-time) ----
#pragma unroll
        for (int r = 0; r < 4; ++r) {
            float4* dst = (float4*)&u[(row0 + r) * FSTRIDE + col0];
            dst[0] = make_float4(c[r][0], c[r][1], c[r][2], c[r][3]);
            dst[1] = make_float4(c[r][4], c[r][5], c[r][6], c[r][7]);
        }
        __syncthreads();

        // ---- bilinear sampling of 80 trajectory points ----
        float partial = 0.0f;
        if (tid < TPTS) {
            const float px = pos[n*160 + 2*tid + 0];
            const float py = pos[n*160 + 2*tid + 1];
            const float txn = (px + 50.0f) / 100.0f * 2.0f - 1.0f;
            const float tyn = (py + 50.0f) / 100.0f * 2.0f - 1.0f;
            float fx = (txn + 1.0f) * 0.5f * 127.0f;
            float fy = (tyn + 1.0f) * 0.5f * 127.0f;
            fx = fminf(fmaxf(fx, 0.0f), 127.0f);
            fy = fminf(fmaxf(fy, 0.0f), 127.0f);
            const float x0 = floorf(fx), y0 = floorf(fy);
            const float wx = fx - x0,    wy = fy - y0;
            int x0i = (int)x0; x0i = x0i < 0 ? 0 : (x0i > 127 ? 127 : x0i);
            int y0i = (int)y0; y0i = y0i < 0 ? 0 : (y0i > 127 ? 127 : y0i);
            const int x1i = (x0i + 1 > 127) ? 127 : x0i + 1;
            const int y1i = (y0i + 1 > 127) ? 127 : y0i + 1;
            const float v00 = u[y0i*FSTRIDE + x0i];
            const float v01 = u[y0i*FSTRIDE + x1i];
            const float v10 = u[y1i*FSTRIDE + x0i];
            const float v11 = u[y1i*FSTRIDE + x1i];
            partial = v00*(1.0f-wx)*(1.0f-wy) + v01*wx*(1.0f-wy)
                    + v10*(1.0f-wx)*wy        + v11*wx*wy;
            red[tid] = partial;
        }
        __syncthreads();
        if (tid == 0) {
            float s = 0.0f;
            for (int i = 0; i < TPTS; ++i) s += red[i];
            sampled_sum = s;
        }
    }

    // ---- analytic energies + global reduction ----
    if (tid == 0) {
        const float dlx = pos[n*160 + 2*(TPTS-1) + 0] - p0x;
        const float dly = pos[n*160 + 2*(TPTS-1) + 1] - p0y;
        const float left_drift = dlx * (-hny) + dly * hnx;
        const float e_left  = -left_drift + 2.0f * fmaxf(-left_drift, 0.0f);
        const float e_right =  left_drift + 2.0f * fmaxf( left_drift, 0.0f);
        const float e_lane  = need_field ? -sampled_sum : 0.0f;
        atomicAdd(out, w_lane*e_lane + w_left*e_left + w_right*e_right);
    }
}

extern "C" void kernel_launch(void* const* d_in, const int* in_sizes, int n_in,
                              void* d_out, int out_size, void* d_ws, size_t ws_size,
                              hipStream_t stream) {
    const float* pos  = (const float*)d_in[0];   // agent_positions_flat [N,80,2]
    const float* gw   = (const float*)d_in[1];   // guidance_weights    [N,3]
    const float* head = (const float*)d_in[2];   // initial_headings    [N,2]
    float* out = (float*)d_out;

    const int N = in_sizes[0] / 160;             // 384

    hipMemsetAsync(out, 0, sizeof(float) * out_size, stream);
    guidance_kernel<<<N, 512, 0, stream>>>(pos, gw, head, out);
}

// Round 3
// 81.882 us; speedup vs baseline: 1.8223x; 1.4732x over previous
//
#include <hip/hip_runtime.h>

// GuidanceController round 3: per agent, screened-Poisson Jacobi (50 iters)
// on 128x128, bilinear-sample 80 traj points, analytic drift energies, sum.
//
// Structure: 1 block = 1 agent = 256 threads = 4 waves. Wave w owns rows
// [32w, 32w+32); lane (lr,lc) = (lane>>4, lane&15) owns an 8x8 register tile
// at rows 32w+8*lr, cols 8*lc. Halo exchange:
//   - horizontal + intra-slab vertical: __shfl (lane+-1, lane+-16), no LDS
//   - slab interfaces (4 rows): tiny double-buffered LDS bufs, ONE barrier/iter
// Ping-pong register fields A<->B (2-iter unroll) -> zero copy instructions.
// Field dumped to LDS once after the loop for bilinear sampling.

#define GR      128
#define FSTRIDE 132
#define NPAIRS  25          // 50 Jacobi iterations
#define TPTS    80

__global__ __launch_bounds__(256, 2)
void guidance_kernel(const float* __restrict__ pos,    // [N,80,2]
                     const float* __restrict__ gw,     // [N,3]
                     const float* __restrict__ head,   // [N,2]
                     float* __restrict__ out)
{
    __shared__ __align__(16) float u[GR * FSTRIDE];    // 67584 B (field; low 8KB aliased as bufs)
    __shared__ float red[TPTS];

    float* bufT = u;             // [2 sets][4 waves][128]  top row of each slab
    float* bufB = u + 1024;      // [2 sets][4 waves][128]  bottom row of each slab

    const int n    = blockIdx.x;
    const int tid  = threadIdx.x;
    const int w    = tid >> 6;      // wave 0..3
    const int lane = tid & 63;
    const int lr   = lane >> 4;     // lane-row 0..3 (8 grid rows each)
    const int lc   = lane & 15;     // lane-col 0..15 (8 grid cols each)
    const int r0   = w * 32 + lr * 8;
    const int c0   = lc * 8;

    // ---- per-agent scalars ----
    const float hx = head[2*n+0], hy = head[2*n+1];
    const float ih  = 1.0f / fmaxf(sqrtf(hx*hx + hy*hy), 1e-12f);
    const float hnx = hx * ih, hny = hy * ih;
    const float p0x = pos[n*160 + 0];
    const float p0y = pos[n*160 + 1];

    const float w_lane  = gw[3*n+0];
    const float w_left  = gw[3*n+1];
    const float w_right = gw[3*n+2];
    const bool need_field = (w_lane > 1e-4f);   // block-uniform

    const float DXf = (float)(100.0 / 127.0);
    const float gclx = fminf(fmaxf(p0x + hnx * 50.0f, -50.0f), 50.0f);
    const float gcly = fminf(fmaxf(p0y + hny * 50.0f, -50.0f), 50.0f);
    const int gxi = (int)((gclx + 50.0f) / DXf);
    const int gyi = (int)((gcly + 50.0f) / DXf);

    const float INV_DENOM =
        (float)(1.0 / (4.0 + 0.01 * (100.0/127.0) * (100.0/127.0)));

    float sampled_sum = 0.0f;

    if (need_field) {
        const int psr = gyi - r0;
        const int psc = gxi - c0;
        const bool own = (psr >= 0 && psr < 8 && psc >= 0 && psc < 8);

        float A[8][8], B[8][8];
#pragma unroll
        for (int r = 0; r < 8; ++r)
#pragma unroll
            for (int j = 0; j < 8; ++j)
                A[r][j] = 0.5f;
        if (own) {
#pragma unroll
            for (int r = 0; r < 8; ++r)
#pragma unroll
                for (int j = 0; j < 8; ++j)
                    if (r == psr && j == psc) A[r][j] = 1.0f;
        }

        auto step = [&](const float (&S)[8][8], float (&D)[8][8], const int s) {
            // ---- publish slab-interface rows (1/4 of lanes each, tiny) ----
            if (lr == 0) {
                float4* p = (float4*)&bufT[(s*4 + w)*128 + c0];
                p[0] = make_float4(S[0][0], S[0][1], S[0][2], S[0][3]);
                p[1] = make_float4(S[0][4], S[0][5], S[0][6], S[0][7]);
            }
            if (lr == 3) {
                float4* p = (float4*)&bufB[(s*4 + w)*128 + c0];
                p[0] = make_float4(S[7][0], S[7][1], S[7][2], S[7][3]);
                p[1] = make_float4(S[7][4], S[7][5], S[7][6], S[7][7]);
            }

            // ---- in-wave halo exchange (pre-update values) ----
            float th[8], bh[8], lh[8], rh[8];
#pragma unroll
            for (int j = 0; j < 8; ++j) th[j] = __shfl(S[7][j], lane - 16);
#pragma unroll
            for (int j = 0; j < 8; ++j) bh[j] = __shfl(S[0][j], lane + 16);
#pragma unroll
            for (int r = 0; r < 8; ++r) lh[r] = __shfl(S[r][7], lane - 1);
#pragma unroll
            for (int r = 0; r < 8; ++r) rh[r] = __shfl(S[r][0], lane + 1);

            __syncthreads();   // publish(s) visible; prev iter's reads long done

            // ---- slab-edge halos from LDS (or grid-boundary zeros) ----
            if (lr == 0) {
                if (w == 0) {
#pragma unroll
                    for (int j = 0; j < 8; ++j) th[j] = 0.0f;
                } else {
                    const float4* p = (const float4*)&bufB[(s*4 + (w-1))*128 + c0];
                    const float4 x = p[0], y = p[1];
                    th[0]=x.x; th[1]=x.y; th[2]=x.z; th[3]=x.w;
                    th[4]=y.x; th[5]=y.y; th[6]=y.z; th[7]=y.w;
                }
            }
            if (lr == 3) {
                if (w == 3) {
#pragma unroll
                    for (int j = 0; j < 8; ++j) bh[j] = 0.0f;
                } else {
                    const float4* p = (const float4*)&bufT[(s*4 + (w+1))*128 + c0];
                    const float4 x = p[0], y = p[1];
                    bh[0]=x.x; bh[1]=x.y; bh[2]=x.z; bh[3]=x.w;
                    bh[4]=y.x; bh[5]=y.y; bh[6]=y.z; bh[7]=y.w;
                }
            }
            if (lc == 0) {
#pragma unroll
                for (int r = 0; r < 8; ++r) lh[r] = 0.0f;
            }
            if (lc == 15) {
#pragma unroll
                for (int r = 0; r < 8; ++r) rh[r] = 0.0f;
            }

            // ---- Jacobi update: all operands registers, no copies ----
#pragma unroll
            for (int r = 0; r < 8; ++r)
#pragma unroll
                for (int j = 0; j < 8; ++j) {
                    const float up = (r == 0) ? th[j] : S[r-1][j];
                    const float dn = (r == 7) ? bh[j] : S[r+1][j];
                    const float lf = (j == 0) ? lh[r] : S[r][j-1];
                    const float rt = (j == 7) ? rh[r] : S[r][j+1];
                    D[r][j] = (up + dn + lf + rt) * INV_DENOM;
                }
            if (own) {
#pragma unroll
                for (int r = 0; r < 8; ++r)
#pragma unroll
                    for (int j = 0; j < 8; ++j)
                        if (r == psr && j == psc) D[r][j] = 1.0f;   // Dirichlet pin
            }
        };

#pragma unroll 1
        for (int p = 0; p < NPAIRS; ++p) {
            step(A, B, 0);
            step(B, A, 1);
        }

        __syncthreads();   // all waves done reading bufs (about to overwrite)

        // ---- dump field to LDS (one-time) ----
#pragma unroll
        for (int r = 0; r < 8; ++r) {
            float4* dst = (float4*)&u[(r0 + r) * FSTRIDE + c0];
            dst[0] = make_float4(A[r][0], A[r][1], A[r][2], A[r][3]);
            dst[1] = make_float4(A[r][4], A[r][5], A[r][6], A[r][7]);
        }
        __syncthreads();

        // ---- bilinear sampling of 80 trajectory points ----
        if (tid < TPTS) {
            const float px = pos[n*160 + 2*tid + 0];
            const float py = pos[n*160 + 2*tid + 1];
            const float txn = (px + 50.0f) / 100.0f * 2.0f - 1.0f;
            const float tyn = (py + 50.0f) / 100.0f * 2.0f - 1.0f;
            float fx = (txn + 1.0f) * 0.5f * 127.0f;
            float fy = (tyn + 1.0f) * 0.5f * 127.0f;
            fx = fminf(fmaxf(fx, 0.0f), 127.0f);
            fy = fminf(fmaxf(fy, 0.0f), 127.0f);
            const float x0 = floorf(fx), y0 = floorf(fy);
            const float wx = fx - x0,    wy = fy - y0;
            int x0i = (int)x0; x0i = x0i < 0 ? 0 : (x0i > 127 ? 127 : x0i);
            int y0i = (int)y0; y0i = y0i < 0 ? 0 : (y0i > 127 ? 127 : y0i);
            const int x1i = (x0i + 1 > 127) ? 127 : x0i + 1;
            const int y1i = (y0i + 1 > 127) ? 127 : y0i + 1;
            const float v00 = u[y0i*FSTRIDE + x0i];
            const float v01 = u[y0i*FSTRIDE + x1i];
            const float v10 = u[y1i*FSTRIDE + x0i];
            const float v11 = u[y1i*FSTRIDE + x1i];
            red[tid] = v00*(1.0f-wx)*(1.0f-wy) + v01*wx*(1.0f-wy)
                     + v10*(1.0f-wx)*wy        + v11*wx*wy;
        }
        __syncthreads();

        // ---- parallel reduce of the 80 samples (wave 0) ----
        if (w == 0) {
            float v = red[lane];
            v += (lane < TPTS - 64) ? red[64 + lane] : 0.0f;
#pragma unroll
            for (int off = 32; off > 0; off >>= 1)
                v += __shfl_down(v, off);
            if (lane == 0) sampled_sum = v;
        }
    }

    // ---- analytic energies + global reduction ----
    if (tid == 0) {
        const float dlx = pos[n*160 + 2*(TPTS-1) + 0] - p0x;
        const float dly = pos[n*160 + 2*(TPTS-1) + 1] - p0y;
        const float left_drift = dlx * (-hny) + dly * hnx;
        const float e_left  = -left_drift + 2.0f * fmaxf(-left_drift, 0.0f);
        const float e_right =  left_drift + 2.0f * fmaxf( left_drift, 0.0f);
        const float e_lane  = need_field ? -sampled_sum : 0.0f;
        atomicAdd(out, w_lane*e_lane + w_left*e_left + w_right*e_right);
    }
}

extern "C" void kernel_launch(void* const* d_in, const int* in_sizes, int n_in,
                              void* d_out, int out_size, void* d_ws, size_t ws_size,
                              hipStream_t stream) {
    const float* pos  = (const float*)d_in[0];   // agent_positions_flat [N,80,2]
    const float* gw   = (const float*)d_in[1];   // guidance_weights    [N,3]
    const float* head = (const float*)d_in[2];   // initial_headings    [N,2]
    float* out = (float*)d_out;

    const int N = in_sizes[0] / 160;             // 384

    hipMemsetAsync(out, 0, sizeof(float) * out_size, stream);
    guidance_kernel<<<N, 256, 0, stream>>>(pos, gw, head, out);
}

// Round 4
// 81.641 us; speedup vs baseline: 1.8277x; 1.0030x over previous
//
#include <hip/hip_runtime.h>

// GuidanceController round 4: per agent, screened-Poisson Jacobi (50 iters)
// on 128x128, bilinear-sample 80 traj points, analytic drift energies, sum.
//
// Round-3 structure kept (4 waves/block, 8x8 register tiles, shfl halos,
// tiny double-buffered slab-interface LDS, ONE barrier per Jacobi step).
// Round-4 change: LDS shrunk 68KB -> ~35KB. The full-field dump is replaced
// by TWO sampling passes over half-fields (rows 0..64 incl. shared row, then
// rows 64..127) reusing one 65x132 f32 buffer. LDS no longer caps residency
// at 2 blocks/CU; __launch_bounds__(256,3) asks for 3 waves/SIMD.

#define GR      128
#define FSTRIDE 132
#define HROWS   65          // half-field rows kept in LDS (incl. boundary row)
#define NPAIRS  25          // 50 Jacobi iterations
#define TPTS    80

__global__ __launch_bounds__(256, 3)
void guidance_kernel(const float* __restrict__ pos,    // [N,80,2]
                     const float* __restrict__ gw,     // [N,3]
                     const float* __restrict__ head,   // [N,2]
                     float* __restrict__ out)
{
    __shared__ __align__(16) float u[HROWS * FSTRIDE]; // 34320 B; low 8KB doubles as halo bufs
    __shared__ float red[TPTS];

    float* bufT = u;             // [2 sets][4 waves][128] top row of each slab
    float* bufB = u + 1024;      // [2 sets][4 waves][128] bottom row of each slab

    const int n    = blockIdx.x;
    const int tid  = threadIdx.x;
    const int w    = tid >> 6;      // wave 0..3
    const int lane = tid & 63;
    const int lr   = lane >> 4;     // lane-row 0..3 (8 grid rows each)
    const int lc   = lane & 15;     // lane-col 0..15 (8 grid cols each)
    const int r0   = w * 32 + lr * 8;
    const int c0   = lc * 8;

    // ---- per-agent scalars ----
    const float hx = head[2*n+0], hy = head[2*n+1];
    const float ih  = 1.0f / fmaxf(sqrtf(hx*hx + hy*hy), 1e-12f);
    const float hnx = hx * ih, hny = hy * ih;
    const float p0x = pos[n*160 + 0];
    const float p0y = pos[n*160 + 1];

    const float w_lane  = gw[3*n+0];
    const float w_left  = gw[3*n+1];
    const float w_right = gw[3*n+2];
    const bool need_field = (w_lane > 1e-4f);   // block-uniform

    const float DXf = (float)(100.0 / 127.0);
    const float gclx = fminf(fmaxf(p0x + hnx * 50.0f, -50.0f), 50.0f);
    const float gcly = fminf(fmaxf(p0y + hny * 50.0f, -50.0f), 50.0f);
    const int gxi = (int)((gclx + 50.0f) / DXf);
    const int gyi = (int)((gcly + 50.0f) / DXf);

    const float INV_DENOM =
        (float)(1.0 / (4.0 + 0.01 * (100.0/127.0) * (100.0/127.0)));

    float sampled_sum = 0.0f;

    if (need_field) {
        const int psr = gyi - r0;
        const int psc = gxi - c0;
        const bool own = (psr >= 0 && psr < 8 && psc >= 0 && psc < 8);

        float A[8][8], B[8][8];
#pragma unroll
        for (int r = 0; r < 8; ++r)
#pragma unroll
            for (int j = 0; j < 8; ++j)
                A[r][j] = 0.5f;
        if (own) {
#pragma unroll
            for (int r = 0; r < 8; ++r)
#pragma unroll
                for (int j = 0; j < 8; ++j)
                    if (r == psr && j == psc) A[r][j] = 1.0f;
        }

        auto step = [&](const float (&S)[8][8], float (&D)[8][8], const int s) {
            // ---- publish slab-interface rows (1/4 of lanes each, tiny) ----
            if (lr == 0) {
                float4* p = (float4*)&bufT[(s*4 + w)*128 + c0];
                p[0] = make_float4(S[0][0], S[0][1], S[0][2], S[0][3]);
                p[1] = make_float4(S[0][4], S[0][5], S[0][6], S[0][7]);
            }
            if (lr == 3) {
                float4* p = (float4*)&bufB[(s*4 + w)*128 + c0];
                p[0] = make_float4(S[7][0], S[7][1], S[7][2], S[7][3]);
                p[1] = make_float4(S[7][4], S[7][5], S[7][6], S[7][7]);
            }

            // ---- in-wave halo exchange (pre-update values) ----
            float th[8], bh[8], lh[8], rh[8];
#pragma unroll
            for (int j = 0; j < 8; ++j) th[j] = __shfl(S[7][j], lane - 16);
#pragma unroll
            for (int j = 0; j < 8; ++j) bh[j] = __shfl(S[0][j], lane + 16);
#pragma unroll
            for (int r = 0; r < 8; ++r) lh[r] = __shfl(S[r][7], lane - 1);
#pragma unroll
            for (int r = 0; r < 8; ++r) rh[r] = __shfl(S[r][0], lane + 1);

            __syncthreads();   // publish(s) visible; prev iter's reads long done

            // ---- slab-edge halos from LDS (or grid-boundary zeros) ----
            if (lr == 0) {
                if (w == 0) {
#pragma unroll
                    for (int j = 0; j < 8; ++j) th[j] = 0.0f;
                } else {
                    const float4* p = (const float4*)&bufB[(s*4 + (w-1))*128 + c0];
                    const float4 x = p[0], y = p[1];
                    th[0]=x.x; th[1]=x.y; th[2]=x.z; th[3]=x.w;
                    th[4]=y.x; th[5]=y.y; th[6]=y.z; th[7]=y.w;
                }
            }
            if (lr == 3) {
                if (w == 3) {
#pragma unroll
                    for (int j = 0; j < 8; ++j) bh[j] = 0.0f;
                } else {
                    const float4* p = (const float4*)&bufT[(s*4 + (w+1))*128 + c0];
                    const float4 x = p[0], y = p[1];
                    bh[0]=x.x; bh[1]=x.y; bh[2]=x.z; bh[3]=x.w;
                    bh[4]=y.x; bh[5]=y.y; bh[6]=y.z; bh[7]=y.w;
                }
            }
            if (lc == 0) {
#pragma unroll
                for (int r = 0; r < 8; ++r) lh[r] = 0.0f;
            }
            if (lc == 15) {
#pragma unroll
                for (int r = 0; r < 8; ++r) rh[r] = 0.0f;
            }

            // ---- Jacobi update: all operands registers, no copies ----
#pragma unroll
            for (int r = 0; r < 8; ++r)
#pragma unroll
                for (int j = 0; j < 8; ++j) {
                    const float up = (r == 0) ? th[j] : S[r-1][j];
                    const float dn = (r == 7) ? bh[j] : S[r+1][j];
                    const float lf = (j == 0) ? lh[r] : S[r][j-1];
                    const float rt = (j == 7) ? rh[r] : S[r][j+1];
                    D[r][j] = (up + dn + lf + rt) * INV_DENOM;
                }
            if (own) {
#pragma unroll
                for (int r = 0; r < 8; ++r)
#pragma unroll
                    for (int j = 0; j < 8; ++j)
                        if (r == psr && j == psc) D[r][j] = 1.0f;   // Dirichlet pin
            }
        };

#pragma unroll 1
        for (int p = 0; p < NPAIRS; ++p) {
            step(A, B, 0);
            step(B, A, 1);
        }

        // ---- precompute sample-point coords (tid < 80) ----
        float wx = 0.f, wy = 0.f;
        int x0i = 0, y0i = 0, x1i = 0, y1i = 0;
        if (tid < TPTS) {
            const float px = pos[n*160 + 2*tid + 0];
            const float py = pos[n*160 + 2*tid + 1];
            const float txn = (px + 50.0f) / 100.0f * 2.0f - 1.0f;
            const float tyn = (py + 50.0f) / 100.0f * 2.0f - 1.0f;
            float fx = (txn + 1.0f) * 0.5f * 127.0f;
            float fy = (tyn + 1.0f) * 0.5f * 127.0f;
            fx = fminf(fmaxf(fx, 0.0f), 127.0f);
            fy = fminf(fmaxf(fy, 0.0f), 127.0f);
            const float x0 = floorf(fx), y0 = floorf(fy);
            wx = fx - x0;  wy = fy - y0;
            x0i = (int)x0; x0i = x0i < 0 ? 0 : (x0i > 127 ? 127 : x0i);
            y0i = (int)y0; y0i = y0i < 0 ? 0 : (y0i > 127 ? 127 : y0i);
            x1i = (x0i + 1 > 127) ? 127 : x0i + 1;
            y1i = (y0i + 1 > 127) ? 127 : y0i + 1;
        }

        // ---- two half-field sampling passes (reuses 65x132 LDS buffer) ----
        float partial = 0.0f;
#pragma unroll 1
        for (int pass = 0; pass < 2; ++pass) {
            __syncthreads();   // bufs (pass0) / prev half-field reads done
            const int base = pass * 64;
#pragma unroll
            for (int r = 0; r < 8; ++r) {
                const int row = r0 + r;
                const bool dump = pass == 0 ? (row <= 64) : (row >= 64);
                if (dump) {
                    float4* dst = (float4*)&u[(row - base) * FSTRIDE + c0];
                    dst[0] = make_float4(A[r][0], A[r][1], A[r][2], A[r][3]);
                    dst[1] = make_float4(A[r][4], A[r][5], A[r][6], A[r][7]);
                }
            }
            __syncthreads();
            if (tid < TPTS && (pass == 0 ? (y0i <= 63) : (y0i >= 64))) {
                const float v00 = u[(y0i - base)*FSTRIDE + x0i];
                const float v01 = u[(y0i - base)*FSTRIDE + x1i];
                const float v10 = u[(y1i - base)*FSTRIDE + x0i];
                const float v11 = u[(y1i - base)*FSTRIDE + x1i];
                partial = v00*(1.0f-wx)*(1.0f-wy) + v01*wx*(1.0f-wy)
                        + v10*(1.0f-wx)*wy        + v11*wx*wy;
            }
        }
        if (tid < TPTS) red[tid] = partial;
        __syncthreads();

        // ---- parallel reduce of the 80 samples (wave 0) ----
        if (w == 0) {
            float v = red[lane];
            v += (lane < TPTS - 64) ? red[64 + lane] : 0.0f;
#pragma unroll
            for (int off = 32; off > 0; off >>= 1)
                v += __shfl_down(v, off);
            if (lane == 0) sampled_sum = v;
        }
    }

    // ---- analytic energies + global reduction ----
    if (tid == 0) {
        const float dlx = pos[n*160 + 2*(TPTS-1) + 0] - p0x;
        const float dly = pos[n*160 + 2*(TPTS-1) + 1] - p0y;
        const float left_drift = dlx * (-hny) + dly * hnx;
        const float e_left  = -left_drift + 2.0f * fmaxf(-left_drift, 0.0f);
        const float e_right =  left_drift + 2.0f * fmaxf( left_drift, 0.0f);
        const float e_lane  = need_field ? -sampled_sum : 0.0f;
        atomicAdd(out, w_lane*e_lane + w_left*e_left + w_right*e_right);
    }
}

extern "C" void kernel_launch(void* const* d_in, const int* in_sizes, int n_in,
                              void* d_out, int out_size, void* d_ws, size_t ws_size,
                              hipStream_t stream) {
    const float* pos  = (const float*)d_in[0];   // agent_positions_flat [N,80,2]
    const float* gw   = (const float*)d_in[1];   // guidance_weights    [N,3]
    const float* head = (const float*)d_in[2];   // initial_headings    [N,2]
    float* out = (float*)d_out;

    const int N = in_sizes[0] / 160;             // 384

    hipMemsetAsync(out, 0, sizeof(float) * out_size, stream);
    guidance_kernel<<<N, 256, 0, stream>>>(pos, gw, head, out);
}